// Round 12
// baseline (65.075 us; speedup 1.0000x reference)
//
#include <hip/hip_runtime.h>
#include <hip/hip_bf16.h>

// StatDynamicConv2d: routing MLP -> expert-mixed 3x3 conv (per-sample weights)
// B=32, Cin=Cout=128, H=W=64, E=4, K=3, pad=1, stride=1.
//
// ws layout:
//   [512, 512+16384)       dynb[32][128] f32
//   [32768, +9437184)      dynw[32][4cic][9tap][8mi][64lane][8] bf16
//                          (MFMA A-fragment order)
// conv reads x (f32) directly; per-cic restage = two-pass LDS transpose
// done IN-PLACE in xs (pass1: coalesced loads -> packed raw rows; pass2:
// reg-staged gather -> swizzled bf16 layout).

typedef short bf16x8 __attribute__((ext_vector_type(8)));
typedef float f32x4  __attribute__((ext_vector_type(4)));

#define VMWAIT(n) asm volatile("s_waitcnt vmcnt(" #n ")" ::: "memory")
#define LGKM0()   asm volatile("s_waitcnt lgkmcnt(0)" ::: "memory")

static __device__ __forceinline__ unsigned short f2bf(float f) {
    unsigned u = __float_as_uint(f);
    u = u + 0x7FFFu + ((u >> 16) & 1u);   // round-to-nearest-even
    return (unsigned short)(u >> 16);
}

static __device__ __forceinline__ void gl2lds16(const unsigned short* g, unsigned short* l) {
    __builtin_amdgcn_global_load_lds(
        (const __attribute__((address_space(1))) unsigned int*)g,
        (__attribute__((address_space(3))) unsigned int*)l,
        16, 0, 0);
}

// ---------------- kernel P: dynamic weights (router inlined) ----------------
// grid 512 (= 128 co x 4 bgroups), 256 threads
__global__ void prep_kernel(const float* __restrict__ stats, const float* __restrict__ W1,
                            const float* __restrict__ b1, const float* __restrict__ W2,
                            const float* __restrict__ b2, const float* __restrict__ wexp,
                            const float* __restrict__ bexp, unsigned short* __restrict__ dynw,
                            float* __restrict__ dynb)
{
    __shared__ float ls[4*1152];
    __shared__ float lr[32*4];
    const int tid = threadIdx.x;
    const int co  = blockIdx.x & 127;
    const int bg  = blockIdx.x >> 7;

    if (tid < 32) {                   // recompute tiny router MLP per block (cheap)
        float s[6];
#pragma unroll
        for (int i = 0; i < 6; ++i) s[i] = stats[tid*6 + i];
        float h[16];
#pragma unroll
        for (int j = 0; j < 16; ++j) {
            float a = b1[j];
#pragma unroll
            for (int i = 0; i < 6; ++i) a += W1[j*6+i]*s[i];
            h[j] = a > 0.f ? a : 0.f;
        }
        float lg[4];
#pragma unroll
        for (int e = 0; e < 4; ++e) {
            float a = b2[e];
#pragma unroll
            for (int j = 0; j < 16; ++j) a += W2[e*16+j]*h[j];
            lg[e] = a;
        }
        float m = fmaxf(fmaxf(lg[0],lg[1]), fmaxf(lg[2],lg[3]));
        float ex[4], sum = 0.f;
#pragma unroll
        for (int e = 0; e < 4; ++e) { ex[e] = expf(lg[e]-m); sum += ex[e]; }
        float inv = 1.f / sum;
#pragma unroll
        for (int e = 0; e < 4; ++e) lr[tid*4+e] = ex[e]*inv;
    }
    for (int i = tid; i < 4*1152; i += 256) {
        int e = i / 1152, j = i - e*1152;
        ls[i] = wexp[((unsigned long long)(e*128 + co))*1152 + j];
    }
    __syncthreads();

    if (bg == 0 && tid < 32) {
        float sb = 0.f;
#pragma unroll
        for (int e = 0; e < 4; ++e) sb += lr[tid*4+e] * bexp[e*128 + co];
        dynb[tid*128 + co] = sb;
    }

    const int ci  = tid & 127;
    const int tp0 = tid >> 7;
    const int cic = ci >> 5;
    const int g   = (ci >> 3) & 3;
    const int jj  = ci & 7;
    const int mi  = co >> 4;
    const int l15 = co & 15;
    for (int bb = bg*8; bb < bg*8 + 8; ++bb) {
        float r0 = lr[bb*4+0], r1 = lr[bb*4+1], r2 = lr[bb*4+2], r3 = lr[bb*4+3];
#pragma unroll
        for (int pp = 0; pp < 5; ++pp) {
            int tap = 2*pp + tp0;
            if (tap < 9) {
                int j = ci*9 + tap;
                float v = r0*ls[j] + r1*ls[1152+j] + r2*ls[2*1152+j] + r3*ls[3*1152+j];
                dynw[((((unsigned long long)(bb*4 + cic)*9 + tap)*8 + mi)*64 + g*16 + l15)*8 + jj] = f2bf(v);
            }
        }
    }
}

// ---------------- kernel D: implicit-GEMM conv, bf16 MFMA ----------------
// grid 512 (32 b x 16 4-row tiles), 256 threads (4 waves), wave = 1 output
// row x full 128 co (mi=8). Weights staged to LDS (6-deep rotation, one
// vmcnt(0)+s_barrier per 3-tap phase). Per-cic x restage: two-pass LDS
// transpose in-place in xs (coalesced loads, no shuffles).
__global__ __launch_bounds__(256, 2) void conv_kernel(
    const float* __restrict__ x,
    const unsigned short* __restrict__ dynw,
    const float* __restrict__ dynb,
    float* __restrict__ out)
{
    __shared__ __align__(16) unsigned short xs[6*66*32];      // 25344 B (6 rows x 4224 B)
    __shared__ __align__(16) unsigned short wsm[6][4096];     // 49152 B

    const int tid  = threadIdx.x;
    const int wave = tid >> 6;       // output row within tile (0..3)
    const int lane = tid & 63;
    const int l15  = lane & 15;
    const int g    = lane >> 4;
    const int pr    = tid >> 4;      // pass1: ci-pair id (0..15)
    const int c4    = tid & 15;      // pass1: col quad (0..15)
    const int p2col = tid & 63;      // pass2: column (0..63)
    const int p2cg  = tid >> 6;      // pass2: 8-ci chunk (0..3)

    // bijective XCD swizzle (512 blocks, 8 XCDs -> 64 contiguous per XCD)
    int bidx = ((blockIdx.x & 7) << 6) | (blockIdx.x >> 3);
    const int b  = bidx >> 4;
    const int r0 = (bidx & 15) << 2;

    f32x4 acc[8][4];
#pragma unroll
    for (int mi = 0; mi < 8; ++mi)
#pragma unroll
        for (int ni = 0; ni < 4; ++ni) acc[mi][ni] = (f32x4){0.f,0.f,0.f,0.f};

    const float* xsrcb = x + (unsigned long long)b*(128ull*64*64);
    const unsigned short* wsrcb = dynw + (unsigned long long)b*(4ull*9*4096);

    // ---- pass1: thread (pr,c4) loads ci 2pr,2pr+1 x cols 4c4..4c4+3 of row kk,
    //      packs bf16 pairs, writes raw uint4 into xs[row][bytes 0..4096) ----
#define P1ISSUE(kk)                                                            \
    do {                                                                       \
        int grow_ = r0 + (kk) - 1;                                             \
        int growc_ = grow_ < 0 ? 0 : (grow_ > 63 ? 63 : grow_);                \
        const float* xp_ = xsrcb + (unsigned)((cic_*32 + 2*pr)*4096)           \
                         + growc_*64 + c4*4;                                   \
        xv[(kk)%3][0] = *(const float4*)xp_;                                   \
        xv[(kk)%3][1] = *(const float4*)(xp_ + 4096);                          \
    } while (0)

#define P1PROC(kk)                                                             \
    do {                                                                       \
        int grow_ = r0 + (kk) - 1;                                             \
        bool oob_ = (grow_ < 0) || (grow_ > 63);                               \
        float4 va_ = xv[(kk)%3][0], vb_ = xv[(kk)%3][1];                       \
        unsigned w0_ = oob_ ? 0u : (f2bf(va_.x) | ((unsigned)f2bf(vb_.x) << 16)); \
        unsigned w1_ = oob_ ? 0u : (f2bf(va_.y) | ((unsigned)f2bf(vb_.y) << 16)); \
        unsigned w2_ = oob_ ? 0u : (f2bf(va_.z) | ((unsigned)f2bf(vb_.z) << 16)); \
        unsigned w3_ = oob_ ? 0u : (f2bf(va_.w) | ((unsigned)f2bf(vb_.w) << 16)); \
        *(uint4*)((char*)xs + (kk)*4224 + pr*256 + c4*16)                      \
            = make_uint4(w0_, w1_, w2_, w3_);                                  \
    } while (0)

    // ---- full restage: issue W(next phase) first, then rolling pass1 ladder,
    //      then in-place pass2 (reg-staged gather with barrier between R/W) ----
#define XSTAGE2(CIC_, WFIRST_)                                                 \
    do {                                                                       \
        const int cic_ = (CIC_);                                               \
        _Pragma("unroll")                                                      \
        for (int t = 0; t < 3; ++t) {                                          \
            const unsigned short* wsrc_ = wsrcb + (unsigned)(((WFIRST_) + t)*4096); \
            unsigned short* wd_ = wsm[((WFIRST_) + t) % 6];                    \
            gl2lds16(wsrc_ + (unsigned)tid*8,       wd_ + (unsigned)tid*8);    \
            gl2lds16(wsrc_ + (unsigned)(tid+256)*8, wd_ + (unsigned)(tid+256)*8); \
        }                                                                      \
        float4 xv[3][2];                                                       \
        P1ISSUE(0); P1ISSUE(1); P1ISSUE(2);                                    \
        VMWAIT(4); P1PROC(0); P1ISSUE(3);                                      \
        VMWAIT(4); P1PROC(1); P1ISSUE(4);                                      \
        VMWAIT(4); P1PROC(2); P1ISSUE(5);                                      \
        VMWAIT(4); P1PROC(3);                                                  \
        VMWAIT(2); P1PROC(4);                                                  \
        VMWAIT(0); P1PROC(5);                                                  \
        LGKM0();                                                               \
        __builtin_amdgcn_s_barrier();                                          \
        __builtin_amdgcn_sched_barrier(0);                                     \
        uint4 tv[6];                                                           \
        _Pragma("unroll")                                                      \
        for (int r = 0; r < 6; ++r) {                                          \
            const char* rb_ = (const char*)xs + r*4224 + p2cg*1024 + p2col*4;  \
            tv[r].x = *(const unsigned*)(rb_);                                 \
            tv[r].y = *(const unsigned*)(rb_ + 256);                           \
            tv[r].z = *(const unsigned*)(rb_ + 512);                           \
            tv[r].w = *(const unsigned*)(rb_ + 768);                           \
        }                                                                      \
        LGKM0();                                                               \
        __builtin_amdgcn_s_barrier();                                          \
        __builtin_amdgcn_sched_barrier(0);                                     \
        {                                                                      \
            int lcol_ = p2col + 1;                                             \
            int wb_   = ((p2cg + (lcol_ >> 1)) & 3) << 4;                      \
            _Pragma("unroll")                                                  \
            for (int r = 0; r < 6; ++r)                                        \
                *(uint4*)((char*)xs + r*4224 + lcol_*64 + wb_) = tv[r];        \
        }                                                                      \
        if (tid < 24)                                                          \
            *(uint4*)((char*)xs + (tid>>2)*4224 + (tid&3)*16)                  \
                = make_uint4(0,0,0,0);                                         \
        LGKM0();                                                               \
        __builtin_amdgcn_s_barrier();                                          \
        __builtin_amdgcn_sched_barrier(0);                                     \
    } while (0)

    // prologue: zero lcol65 (never touched by restage), stage cic0 + W(0..2)
    if (tid < 24)
        *(uint4*)((char*)xs + (tid>>2)*4224 + 65*64 + (tid&3)*16) = make_uint4(0,0,0,0);
    XSTAGE2(0, 0);

#pragma unroll
    for (int p = 0; p < 12; ++p) {
        const int cic = p / 3;
        if (p > 0) {
            // bar A: W(p) (issued a full phase ago) landed; cheap drain
            VMWAIT(0);
            __builtin_amdgcn_s_barrier();
            __builtin_amdgcn_sched_barrier(0);
        }
        if ((p % 3) == 0 && p > 0) {
            // cic boundary: restage xs in-place (coalesced 2-pass transpose);
            // issues W(3p+3..3p+5) inside; ends with barrier.
            XSTAGE2(cic, 3*p + 3);
        } else if (p < 11) {
            // steady: issue next phase's 3 weight tiles (reads {3p..3p+2}%6,
            // writes {3p+3..3p+5}%6 — disjoint)
#pragma unroll
            for (int t = 0; t < 3; ++t) {
                const int s = 3*p + 3 + t;
                const unsigned short* wsrc = wsrcb + (unsigned)(s*4096);
                unsigned short* wd = wsm[s % 6];
                gl2lds16(wsrc + (unsigned)tid*8,       wd + (unsigned)tid*8);
                gl2lds16(wsrc + (unsigned)(tid+256)*8, wd + (unsigned)(tid+256)*8);
            }
        }
        // compute 3 taps (ky = p%3, kx = 0..2), no intervening sync
        const int ky   = p % 3;
        const int lrow = wave + ky;
        __builtin_amdgcn_s_setprio(1);
#pragma unroll
        for (int kx = 0; kx < 3; ++kx) {
            const unsigned short* wb = wsm[(3*p + kx) % 6];
            bf16x8 afrag[8];
#pragma unroll
            for (int mi = 0; mi < 8; ++mi)
                afrag[mi] = *(const bf16x8*)(wb + (unsigned)((mi*64 + lane)*8));
#pragma unroll
            for (int ni = 0; ni < 4; ++ni) {
                int lcol = 16*ni + l15 + kx;
                int boff = (lrow*66 + lcol)*64 + (((g + (lcol >> 1)) & 3) << 4);
                bf16x8 bfrag = *(const bf16x8*)((const char*)xs + boff);
#pragma unroll
                for (int mi = 0; mi < 8; ++mi)
                    acc[mi][ni] = __builtin_amdgcn_mfma_f32_16x16x32_bf16(
                                      afrag[mi], bfrag, acc[mi][ni], 0, 0, 0);
            }
        }
        __builtin_amdgcn_s_setprio(0);
    }

    // epilogue: co = 16*mi + g*4 + r ; y = r0 + wave ; x = 16*ni + l15
    const int y = r0 + wave;
#pragma unroll
    for (int mi = 0; mi < 8; ++mi) {
#pragma unroll
        for (int r = 0; r < 4; ++r) {
            int co = 16*mi + g*4 + r;
            float bias = dynb[b*128 + co];
            float* op = out + (((unsigned long long)(b*128 + co))*64 + y)*64;
#pragma unroll
            for (int ni = 0; ni < 4; ++ni)
                op[16*ni + l15] = acc[mi][ni][r] + bias;
        }
    }
#undef XSTAGE2
#undef P1PROC
#undef P1ISSUE
}

extern "C" void kernel_launch(void* const* d_in, const int* in_sizes, int n_in,
                              void* d_out, int out_size, void* d_ws, size_t ws_size,
                              hipStream_t stream)
{
    const float* x     = (const float*)d_in[0];
    const float* stats = (const float*)d_in[1];
    const float* W1    = (const float*)d_in[2];
    const float* b1    = (const float*)d_in[3];
    const float* W2    = (const float*)d_in[4];
    const float* b2    = (const float*)d_in[5];
    const float* wexp  = (const float*)d_in[6];
    const float* bexp  = (const float*)d_in[7];
    float* out = (float*)d_out;

    char* ws = (char*)d_ws;
    float* dynb           = (float*)(ws + 512);                      // 16 KB
    unsigned short* dynw  = (unsigned short*)(ws + 32768);           // 9,437,184 B

    prep_kernel<<<512, 256, 0, stream>>>(stats, W1, b1, W2, b2, wexp, bexp, dynw, dynb);
    conv_kernel<<<512, 256, 0, stream>>>(x, dynw, dynb, out);
}